// Round 7
// baseline (3012.012 us; speedup 1.0000x reference)
//
#include <hip/hip_runtime.h>
#include <hip/hip_bf16.h>

// ---------------------------------------------------------------------------
// GCN (3-layer) + encoder + rank_diff stats, all fp32.
// R7: megastats is latency-floor-bound on 4 CUs (572us tail while 252 CUs
//     idle). Hide it: piggyback megastats(stat i) as one extra block on the
//     NEXT layer's syrkstats launch (static block partition). Only stat3's
//     solve remains exposed. syrkstats rewritten for 512 threads to match.
// ---------------------------------------------------------------------------

#define DIM 128

// DPP helpers: 0xB1=quad_perm xor1, 0x4E=quad_perm xor2, 0x124=row_ror:4,
// 0x128=row_ror:8, 0x142=row_bcast15, 0x143=row_bcast31.
template <int CTRL>
__device__ __forceinline__ float dpp_add(float v) {
  int x = __builtin_amdgcn_update_dpp(0, __float_as_int(v), CTRL, 0xF, 0xF, true);
  return v + __int_as_float(x);
}

// full 64-lane sum, result broadcast via readlane(63)
__device__ __forceinline__ float wave_sum(float v) {
  v = dpp_add<0xB1>(v);
  v = dpp_add<0x4E>(v);
  v = dpp_add<0x124>(v);
  v = dpp_add<0x128>(v);
  v = dpp_add<0x142>(v);
  v = dpp_add<0x143>(v);
  return __int_as_float(__builtin_amdgcn_readlane(__float_as_int(v), 63));
}

// ------------------------------- graph setup -------------------------------

__global__ void k_deg(const int* __restrict__ dst, unsigned* __restrict__ deg, int E) {
  int e = blockIdx.x * 256 + threadIdx.x;
  if (e < E) atomicAdd(&deg[dst[e]], 1u);
}

__global__ __launch_bounds__(1024) void k_scan1(const unsigned* __restrict__ deg,
                                                unsigned* __restrict__ loc,
                                                unsigned* __restrict__ part, int n) {
  __shared__ unsigned wtot[16];
  int tid = threadIdx.x, lane = tid & 63, wid = tid >> 6;
  int i = blockIdx.x * 1024 + tid;
  unsigned v = (i < n) ? deg[i] : 0u;
  unsigned s = v;
  #pragma unroll
  for (int d = 1; d < 64; d <<= 1) {
    unsigned t = __shfl_up(s, d);
    if (lane >= d) s += t;
  }
  if (lane == 63) wtot[wid] = s;
  __syncthreads();
  if (tid == 0) {
    unsigned acc = 0;
    #pragma unroll
    for (int w = 0; w < 16; w++) { unsigned t = wtot[w]; wtot[w] = acc; acc += t; }
    part[blockIdx.x] = acc;
  }
  __syncthreads();
  if (i < n) loc[i] = wtot[wid] + (s - v);
}

__global__ void k_scan2(unsigned* part, int nb) {
  int tid = threadIdx.x;  // 64 threads, nb <= 64
  unsigned v = (tid < nb) ? part[tid] : 0u;
  unsigned s = v;
  #pragma unroll
  for (int d = 1; d < 64; d <<= 1) {
    unsigned t = __shfl_up(s, d);
    if (tid >= d) s += t;
  }
  if (tid < nb) part[tid] = s - v;
  if (tid == 63) part[nb] = s;
}

__global__ __launch_bounds__(1024) void k_scan3(const unsigned* __restrict__ deg,
                                                const unsigned* __restrict__ part,
                                                unsigned* __restrict__ rowptr,
                                                unsigned* __restrict__ loc_cursor,
                                                float* __restrict__ dinv, int n, int nb) {
  int i = blockIdx.x * 1024 + threadIdx.x;
  if (i < n) {
    unsigned v = loc_cursor[i] + part[blockIdx.x];
    rowptr[i] = v;
    loc_cursor[i] = v;
    unsigned d = deg[i];
    dinv[i] = d ? 1.0f / sqrtf((float)d) : 0.0f;
  }
  if (i == 0) rowptr[n] = part[nb];
}

__global__ void k_scatter(const int* __restrict__ src, const int* __restrict__ dst,
                          const float* __restrict__ dinv, unsigned* __restrict__ cursor,
                          int* __restrict__ srcs, float* __restrict__ nrm, int E) {
  int e = blockIdx.x * 256 + threadIdx.x;
  if (e >= E) return;
  int s = src[e], d = dst[e];
  unsigned pos = atomicAdd(&cursor[d], 1u);
  srcs[pos] = s;
  nrm[pos] = dinv[s] * dinv[d];
}

// ------------------------------- GEMM: out = A @ W.T (+bias) ----------------

__global__ __launch_bounds__(256, 2) void k_gemm(const float* __restrict__ A,
                                                 const float* __restrict__ W,
                                                 const float* __restrict__ bias,
                                                 float* __restrict__ out, int M) {
  __shared__ float Hs[32][132];   // k-major: Hs[kk][row]
  __shared__ float Ws[32][132];   // k-major: Ws[kk][col]
  const int tid = threadIdx.x;
  const int r0 = blockIdx.x * 128;
  const int tx = tid & 15, ty = tid >> 4;
  const bool full = (r0 + 128 <= M);

  float acc[8][8];
  #pragma unroll
  for (int i = 0; i < 8; i++)
    #pragma unroll
    for (int j = 0; j < 8; j++) acc[i][j] = 0.f;

  #pragma unroll 1
  for (int k0 = 0; k0 < 128; k0 += 32) {
    #pragma unroll
    for (int i = 0; i < 4; i++) {
      int f4 = i * 256 + tid;
      int row = f4 >> 3, kq = f4 & 7;
      int gr = r0 + row;
      float4 v = make_float4(0.f, 0.f, 0.f, 0.f);
      if (full || gr < M) v = *(const float4*)&A[(size_t)gr * 128 + k0 + kq * 4];
      Hs[kq * 4 + 0][row] = v.x; Hs[kq * 4 + 1][row] = v.y;
      Hs[kq * 4 + 2][row] = v.z; Hs[kq * 4 + 3][row] = v.w;
    }
    #pragma unroll
    for (int i = 0; i < 4; i++) {
      int f4 = i * 256 + tid;
      int col = f4 >> 3, kq = f4 & 7;
      float4 v = *(const float4*)&W[(size_t)col * 128 + k0 + kq * 4];
      Ws[kq * 4 + 0][col] = v.x; Ws[kq * 4 + 1][col] = v.y;
      Ws[kq * 4 + 2][col] = v.z; Ws[kq * 4 + 3][col] = v.w;
    }
    __syncthreads();
    #pragma unroll 8
    for (int kk = 0; kk < 32; kk++) {
      float4 a0 = *(const float4*)&Hs[kk][ty * 8];
      float4 a1 = *(const float4*)&Hs[kk][ty * 8 + 4];
      float4 b0 = *(const float4*)&Ws[kk][tx * 8];
      float4 b1 = *(const float4*)&Ws[kk][tx * 8 + 4];
      float a[8] = { a0.x, a0.y, a0.z, a0.w, a1.x, a1.y, a1.z, a1.w };
      float b[8] = { b0.x, b0.y, b0.z, b0.w, b1.x, b1.y, b1.z, b1.w };
      #pragma unroll
      for (int i = 0; i < 8; i++)
        #pragma unroll
        for (int j = 0; j < 8; j++) acc[i][j] += a[i] * b[j];
    }
    __syncthreads();
  }

  float bb[8] = {0.f,0.f,0.f,0.f,0.f,0.f,0.f,0.f};
  if (bias) {
    float4 v0 = *(const float4*)&bias[tx * 8];
    float4 v1 = *(const float4*)&bias[tx * 8 + 4];
    bb[0]=v0.x; bb[1]=v0.y; bb[2]=v0.z; bb[3]=v0.w;
    bb[4]=v1.x; bb[5]=v1.y; bb[6]=v1.z; bb[7]=v1.w;
  }
  #pragma unroll
  for (int i = 0; i < 8; i++) {
    int gr = r0 + ty * 8 + i;
    if (full || gr < M) {
      float4 o0 = make_float4(acc[i][0]+bb[0], acc[i][1]+bb[1], acc[i][2]+bb[2], acc[i][3]+bb[3]);
      float4 o1 = make_float4(acc[i][4]+bb[4], acc[i][5]+bb[5], acc[i][6]+bb[6], acc[i][7]+bb[7]);
      *(float4*)&out[(size_t)gr * 128 + tx * 8] = o0;
      *(float4*)&out[(size_t)gr * 128 + tx * 8 + 4] = o1;
    }
  }
}

// ------------------------------- aggregation -------------------------------

template <bool RELU>
__global__ __launch_bounds__(256) void k_agg(const float* __restrict__ tmp,
                                             const unsigned* __restrict__ rowptr,
                                             const int* __restrict__ srcs,
                                             const float* __restrict__ nrm,
                                             const float* __restrict__ bias,
                                             float* __restrict__ out, int N) {
  int wid = threadIdx.x >> 6, lane = threadIdx.x & 63;
  int n = blockIdx.x * 4 + wid;
  if (n >= N) return;
  unsigned e0 = rowptr[n], e1 = rowptr[n + 1];
  float ax = 0.f, ay = 0.f;
  unsigned e = e0;
  for (; e + 2 <= e1; e += 2) {
    int s0 = srcs[e], s1 = srcs[e + 1];
    float w0 = nrm[e], w1 = nrm[e + 1];
    float2 x0 = *(const float2*)&tmp[(size_t)s0 * 128 + 2 * lane];
    float2 x1 = *(const float2*)&tmp[(size_t)s1 * 128 + 2 * lane];
    ax += w0 * x0.x + w1 * x1.x;
    ay += w0 * x0.y + w1 * x1.y;
  }
  if (e < e1) {
    int s = srcs[e];
    float w = nrm[e];
    float2 x0 = *(const float2*)&tmp[(size_t)s * 128 + 2 * lane];
    ax += w * x0.x;
    ay += w * x0.y;
  }
  float2 bv = *(const float2*)&bias[2 * lane];
  ax += bv.x; ay += bv.y;
  if (RELU) { ax = fmaxf(ax, 0.f); ay = fmaxf(ay, 0.f); }
  float2 o = make_float2(ax, ay);
  *(float2*)&out[(size_t)n * 128 + 2 * lane] = o;
}

// --------------------- SYRK + row/col stats (512-thread body) ---------------
// G += h^T h ; colsum += per-col |h| sums ; packed = argmax row-L1 (u64)

__device__ __forceinline__ void syrk_body(const float* __restrict__ h,
                                          float* __restrict__ G,
                                          float* __restrict__ colsum,
                                          unsigned long long* __restrict__ packed,
                                          int N, int rowsPer) {
  __shared__ float hs[16][132];
  __shared__ float csS[128];
  __shared__ unsigned long long pkS[16];
  const int tid = threadIdx.x;
  const int tx = tid & 31, ty = tid >> 5;       // compute map: 32x16 grid
  const int rr = tid >> 5, c4 = (tid & 31) * 4; // load map: row rr(0..15), col c4
  float acc[8][4];
  #pragma unroll
  for (int i = 0; i < 8; i++)
    #pragma unroll
    for (int j = 0; j < 4; j++) acc[i][j] = 0.f;
  float ca0 = 0.f, ca1 = 0.f, ca2 = 0.f, ca3 = 0.f;
  unsigned long long best = 0;
  if (tid < 128) csS[tid] = 0.f;
  __syncthreads();

  int rstart = blockIdx.x * rowsPer;
  int rend = rstart + rowsPer;
  if (rend > N) rend = N;
  for (int rb = rstart; rb < rend; rb += 16) {
    int gr = rb + rr;
    float4 v = make_float4(0.f, 0.f, 0.f, 0.f);
    if (gr < rend) v = *(const float4*)&h[(size_t)gr * 128 + c4];
    __syncthreads();
    *(float4*)&hs[rr][c4] = v;
    // row/col stats on the loaded tile (each row = one 32-lane group)
    float avx = fabsf(v.x), avy = fabsf(v.y), avz = fabsf(v.z), avw = fabsf(v.w);
    ca0 += avx; ca1 += avy; ca2 += avz; ca3 += avw;
    float rs = (avx + avy) + (avz + avw);
    rs = dpp_add<0xB1>(rs);
    rs = dpp_add<0x4E>(rs);
    rs = dpp_add<0x124>(rs);
    rs = dpp_add<0x128>(rs);
    rs = dpp_add<0x142>(rs);  // lanes 16-31 / 48-63 hold full 32-lane row sums
    if (gr < rend) {
      unsigned long long pk = ((unsigned long long)__float_as_uint(rs) << 32)
                            | (unsigned long long)(0xFFFFFFFFu - (unsigned)gr);
      if (pk > best) best = pk;
    }
    __syncthreads();
    #pragma unroll
    for (int r2 = 0; r2 < 16; r2++) {
      float4 a0 = *(const float4*)&hs[r2][ty * 8];
      float4 a1 = *(const float4*)&hs[r2][ty * 8 + 4];
      float4 b0 = *(const float4*)&hs[r2][tx * 4];
      float a[8] = { a0.x,a0.y,a0.z,a0.w,a1.x,a1.y,a1.z,a1.w };
      float b[4] = { b0.x,b0.y,b0.z,b0.w };
      #pragma unroll
      for (int i = 0; i < 8; i++)
        #pragma unroll
        for (int j = 0; j < 4; j++) acc[i][j] += a[i] * b[j];
    }
  }
  if ((tid & 31) == 16) pkS[tid >> 5] = best;
  atomicAdd(&csS[c4 + 0], ca0);
  atomicAdd(&csS[c4 + 1], ca1);
  atomicAdd(&csS[c4 + 2], ca2);
  atomicAdd(&csS[c4 + 3], ca3);
  __syncthreads();
  if (tid == 0) {
    unsigned long long m = pkS[0];
    #pragma unroll
    for (int w = 1; w < 16; w++) if (pkS[w] > m) m = pkS[w];
    atomicMax(packed, m);
  }
  if (tid < 128) atomicAdd(&colsum[tid], csS[tid]);
  #pragma unroll
  for (int i = 0; i < 8; i++)
    #pragma unroll
    for (int j = 0; j < 4; j++)
      atomicAdd(&G[(size_t)(ty * 8 + i) * 128 + tx * 4 + j], acc[i][j]);
}

__global__ void k_extract(const float* __restrict__ h,
                          const unsigned long long* __restrict__ packed,
                          float* __restrict__ hrow, int N) {
  unsigned long long pk = *packed;
  unsigned i = 0xFFFFFFFFu - (unsigned)(pk & 0xFFFFFFFFull);
  if (i >= (unsigned)N) i = 0;
  hrow[threadIdx.x] = h[(size_t)i * 128 + threadIdx.x];
}

// ------------------------------- megastats body ----------------------------
// One 512-thread block: 2x (tridiag + bisection) trace-sqrt on 128x128 Gram.
// (identical algorithm to R6's k_megastats4, as a device function)

__device__ __forceinline__ void mega_body(const float* __restrict__ Gall,
                                          const float* __restrict__ colall,
                                          const float* __restrict__ hrowall,
                                          float* __restrict__ outstats, int blk) {
  const float* G = Gall + (size_t)blk * 16384;
  const float* colsum = colall + blk * 128;
  const float* hrowg = hrowall + blk * 128;

  __shared__ __align__(16) float colk[128];
  __shared__ __align__(16) float wwF[256];    // ww[2][128] double buffer
  __shared__ __align__(16) float lamp[8];
  __shared__ float sigp[2];
  __shared__ float diag[128], offd[128];
  __shared__ float asS[128], b2S[128];
  __shared__ float loS[128], hiS[128];
  __shared__ float hiRow[128], gjS[128];
  __shared__ int cntS[512];
  __shared__ float redw[8];
  __shared__ float scal[16];
  __shared__ int ishared[4];

  const int tid = threadIdx.x;
  const int lane = tid & 63;
  const int wv = tid >> 6;     // wave 0..7
  const int q = tid >> 7;      // slice 0..3 (wave-pair)
  const int r = tid & 127;     // row
  const int cbase = q * 32;
  float Areg[32];

  #pragma unroll
  for (int cc = 0; cc < 32; cc++) {
    int c = cbase + cc;
    Areg[cc] = 0.5f * (G[(size_t)r * 128 + c] + G[(size_t)c * 128 + r]);
  }

  for (int solve = 0; solve < 2; solve++) {
    if (q == 0) colk[r] = (r == 0) ? 0.f : Areg[0];
    if (tid == 0) diag[0] = Areg[0];
    if (tid < 256) wwF[tid] = 0.f;
    if (q == 0) {
      float m2 = (r >= 1) ? Areg[0] * Areg[0] : 0.f;
      float s = wave_sum(m2);
      if (lane == 0) sigp[wv] = s;   // wv = 0,1
    }
    __syncthreads();

    for (int k = 0; k <= 125; k++) {
      const int kp1 = k + 1;
      float* wwc = &wwF[(k & 1) * 128];
      float* wwn = &wwF[(1 - (k & 1)) * 128];
      // ---- phase A ----
      float sig = sigp[0] + sigp[1];
      float xk1 = colk[kp1];
      float nx = sqrtf(sig);
      float alpha = (xk1 >= 0.f) ? -nx : nx;
      float vns = 2.0f * (sig - alpha * xk1);
      float rvn = (vns > 1e-35f) ? rsqrtf(vns) : 0.f;
      float narvn = -alpha * rvn;
      float ckr = colk[r];
      float vr = ckr * rvn + ((r == kp1) ? narvn : 0.f);
      const bool act = (cbase + 31 >= k);
      float4 cv[8];
      float p = 0.f;
      if (act) {
        const float4* cp = (const float4*)&colk[cbase];  // broadcast reads
        #pragma unroll
        for (int i = 0; i < 8; i++) cv[i] = cp[i];
        if (r >= k) {
          #pragma unroll
          for (int i = 0; i < 8; i++)
            p += Areg[4*i+0]*cv[i].x + Areg[4*i+1]*cv[i].y
               + Areg[4*i+2]*cv[i].z + Areg[4*i+3]*cv[i].w;
          int kl = kp1 - cbase;
          float akp1 = 0.f;
          if (kl >= 0 && kl < 32) {
            #pragma unroll
            for (int i = 0; i < 32; i++) if (i == kl) akp1 = Areg[i];
          }
          p = rvn * p + narvn * akp1;
          atomicAdd(&wwc[r], p);      // ds_add_f32, cross-wave combine
        }
      }
      float lp = vr * p;
      float ls = wave_sum(lp);
      if (lane == 0) lamp[wv] = ls;
      if (tid == 0) offd[k] = alpha;
      __syncthreads();

      // ---- phase B ----
      float4 l0 = *(const float4*)&lamp[0];
      float4 l1 = *(const float4*)&lamp[4];
      float lam = ((l0.x + l0.y) + (l0.z + l0.w)) + ((l1.x + l1.y) + (l1.z + l1.w));
      const int qo = kp1 >> 5;
      float nextc = 0.f;
      if (act && r >= k) {
        float wr = wwc[r];
        float qr = 2.0f * (wr - lam * vr);
        const int kl = kp1 - cbase;
        const float4* wp = (const float4*)&wwc[cbase];   // broadcast reads
        #pragma unroll
        for (int i = 0; i < 8; i++) {
          const int c0 = 4 * i;
          float4 wc = wp[i];
          float v0 = cv[i].x * rvn + ((c0 + 0 == kl) ? narvn : 0.f);
          float v1 = cv[i].y * rvn + ((c0 + 1 == kl) ? narvn : 0.f);
          float v2 = cv[i].z * rvn + ((c0 + 2 == kl) ? narvn : 0.f);
          float v3 = cv[i].w * rvn + ((c0 + 3 == kl) ? narvn : 0.f);
          float q0 = 2.f * (wc.x - lam * v0);
          float q1 = 2.f * (wc.y - lam * v1);
          float q2 = 2.f * (wc.z - lam * v2);
          float q3 = 2.f * (wc.w - lam * v3);
          float a0 = Areg[c0+0] - (vr * q0 + qr * v0); Areg[c0+0] = a0;
          float a1 = Areg[c0+1] - (vr * q1 + qr * v1); Areg[c0+1] = a1;
          float a2 = Areg[c0+2] - (vr * q2 + qr * v2); Areg[c0+2] = a2;
          float a3 = Areg[c0+3] - (vr * q3 + qr * v3); Areg[c0+3] = a3;
          if (c0 + 0 == kl) nextc = a0;
          if (c0 + 1 == kl) nextc = a1;
          if (c0 + 2 == kl) nextc = a2;
          if (c0 + 3 == kl) nextc = a3;
        }
      }
      if (q == qo && r >= k) colk[r] = (r <= kp1) ? 0.f : nextc;
      if (q == qo && r == kp1) diag[kp1] = nextc;
      if (q == qo) {
        float m2 = (r > kp1 && r >= k) ? nextc * nextc : 0.f;
        float s = wave_sum(m2);
        if (lane == 0) sigp[wv & 1] = s;
      }
      if (q == 1) wwn[r] = 0.f;   // zero next buffer
      __syncthreads();
    }
    if (tid == 0) offd[126] = colk[127];
    if (q == 3 && r == 127) diag[127] = Areg[31];
    __syncthreads();

    // ---- Gershgorin bound ----
    if (tid < 128) {
      float t = fabsf(diag[tid]);
      if (tid > 0) t += fabsf(offd[tid - 1]);
      if (tid < 127) t += fabsf(offd[tid]);
      #pragma unroll
      for (int m = 32; m >= 1; m >>= 1) t = fmaxf(t, __shfl_xor(t, m));
      if (lane == 0) redw[wv] = t;
    }
    __syncthreads();
    if (tid == 0) {
      float g = fmaxf(redw[0], redw[1]);
      if (!(g > 1e-30f)) g = 1.f;
      scal[3] = g; scal[5] = 1.0f / g;
    }
    __syncthreads();
    if (tid < 128) {
      float ginv = scal[5];
      asS[tid] = diag[tid] * ginv;
      float ob = (tid < 127) ? offd[tid] * ginv : 0.f;
      b2S[tid] = ob * ob;
      loS[tid] = -0.0625f;
      hiS[tid] = 1.03125f;
    }
    __syncthreads();

    // ---- multisection bisection ----
    for (int round = 0; round < 12; round++) {
      int kk = tid & 127;
      int t = tid >> 7;
      float l = loS[kk], h2v = hiS[kk];
      float sigma = l + (h2v - l) * 0.2f * (float)(t + 1);
      const float PIV = 1e-20f;
      float d = asS[0] - sigma;
      if (fabsf(d) < PIV) d = -PIV;
      int cnt = (d < 0.f) ? 1 : 0;
      for (int i = 1; i < 128; i++) {
        d = (asS[i] - sigma) - b2S[i - 1] * __builtin_amdgcn_rcpf(d);
        if (fabsf(d) < PIV) d = -PIV;
        cnt += (d < 0.f) ? 1 : 0;
      }
      cntS[tid] = cnt;
      __syncthreads();
      if (tid < 128) {
        int c0 = cntS[tid], c1 = cntS[tid + 128], c2 = cntS[tid + 256], c3 = cntS[tid + 384];
        float l2 = loS[tid], h2 = hiS[tid];
        float w = (h2 - l2) * 0.2f;
        int cross = 4;
        if (c0 > tid) cross = 0;
        else if (c1 > tid) cross = 1;
        else if (c2 > tid) cross = 2;
        else if (c3 > tid) cross = 3;
        loS[tid] = (cross == 0) ? l2 : l2 + w * (float)cross;
        hiS[tid] = (cross == 4) ? h2 : l2 + w * (float)(cross + 1);
      }
      __syncthreads();
    }
    // ---- sum sqrt eigenvalues ----
    if (tid < 128) {
      float lam2 = 0.5f * (loS[tid] + hiS[tid]);
      lam2 = fmaxf(lam2, 0.f) * scal[3];
      float s = sqrtf(lam2);
      #pragma unroll
      for (int m = 32; m >= 1; m >>= 1) s += __shfl_xor(s, m);
      if (lane == 0) redw[wv] = s;
    }
    __syncthreads();
    if (tid == 0) scal[4] = redw[0] + redw[1];
    __syncthreads();

    if (solve == 0) {
      if (tid < 128) hiRow[tid] = hrowg[tid];
      __syncthreads();
      if (tid < 128) {
        float v = colsum[tid];
        int idx = tid;
        #pragma unroll
        for (int m = 32; m >= 1; m >>= 1) {
          float v2 = __shfl_xor(v, m);
          int i2 = __shfl_xor(idx, m);
          if (v2 > v || (v2 == v && i2 < idx)) { v = v2; idx = i2; }
        }
        if (lane == 0) { redw[wv] = v; ishared[wv] = idx; }
        float hv = hiRow[tid];
        float nh = hv * hv;
        #pragma unroll
        for (int m = 32; m >= 1; m >>= 1) nh += __shfl_xor(nh, m);
        if (lane == 0) redw[4 + wv] = nh;
      }
      __syncthreads();
      if (tid == 0) {
        float v0 = redw[0], v1 = redw[1];
        int j = (v1 > v0 || (v1 == v0 && ishared[1] < ishared[0])) ? ishared[1] : ishared[0];
        float nh2 = redw[4] + redw[5];
        float nu = scal[4];
        float Gjj = G[(size_t)j * 128 + j];
        float hij = hiRow[j];
        float sflip = (hij < 0.f) ? -1.f : 1.f;
        scal[6] = 1.0f / (nu * nu);
        scal[7] = sflip / (nu * sqrtf(Gjj) * sqrtf(nh2));
        scal[8] = 1.0f / nh2;
        ishared[2] = j;
      }
      __syncthreads();
      int j = ishared[2];
      if (tid < 128) gjS[tid] = 0.5f * (G[(size_t)tid * 128 + j] + G[(size_t)j * 128 + tid]);
      __syncthreads();
      float inv2 = scal[6], c1 = scal[7], c2 = scal[8];
      float gr_ = gjS[r], hr_ = hiRow[r];
      #pragma unroll
      for (int cc = 0; cc < 32; cc++) {
        int c = cbase + cc;
        float gsym = 0.5f * (G[(size_t)r * 128 + c] + G[(size_t)c * 128 + r]);
        Areg[cc] = gsym * inv2 - c1 * (gr_ * hiRow[c] + hr_ * gjS[c]) + c2 * hr_ * hiRow[c];
      }
      __syncthreads();
    }
  }
  if (tid == 0) outstats[blk] = scal[4];
}

// --------------- combined launch: syrkstats blocks + 1 mega block ----------

__global__ __launch_bounds__(512) void k_syrk_mega(const float* __restrict__ h,
                                                   float* __restrict__ G,
                                                   float* __restrict__ colsum,
                                                   unsigned long long* __restrict__ packed,
                                                   int N, int rowsPer, int syrkBlocks,
                                                   const float* __restrict__ Gall,
                                                   const float* __restrict__ colall,
                                                   const float* __restrict__ hrowall,
                                                   float* __restrict__ outstats, int megaIdx) {
  if ((int)blockIdx.x < syrkBlocks) {
    syrk_body(h, G, colsum, packed, N, rowsPer);
  } else if (megaIdx >= 0) {
    mega_body(Gall, colall, hrowall, outstats, megaIdx);
  }
}

// ------------------------------- host driver -------------------------------

extern "C" void kernel_launch(void* const* d_in, const int* in_sizes, int n_in,
                              void* d_out, int out_size, void* d_ws, size_t ws_size,
                              hipStream_t stream) {
  const float* x = (const float*)d_in[0];
  const int* edge = (const int*)d_in[1];
  const float* encW = (const float*)d_in[2];
  const float* encb = (const float*)d_in[3];
  const float* W0 = (const float*)d_in[4];
  const float* b0 = (const float*)d_in[5];
  const float* W1 = (const float*)d_in[6];
  const float* b1 = (const float*)d_in[7];
  const float* W2 = (const float*)d_in[8];
  const float* b2 = (const float*)d_in[9];

  const int N = in_sizes[0] / 128;
  const int E = in_sizes[1] / 2;
  const int* esrc = edge;
  const int* edst = edge + E;

  float* out = (float*)d_out;
  float* stats_out = out + (size_t)N * 128;

  char* ws = (char*)d_ws;
  size_t offTmp = 0;
  size_t offG = offTmp + (size_t)N * 128 * 4;
  size_t offCol = offG + 4 * 16384 * 4;
  size_t offPkd = offCol + 4 * 128 * 4;
  size_t offHrow = offPkd + 4 * 8;
  size_t offDeg = offHrow + 4 * 128 * 4;
  size_t offRp = offDeg + (size_t)N * 4;
  size_t offCur = offRp + (size_t)(N + 1) * 4;
  size_t offDinv = offCur + (size_t)N * 4;
  size_t offSrc = offDinv + (size_t)N * 4;
  size_t offNrm = offSrc + (size_t)E * 4;
  size_t offPart = offNrm + (size_t)E * 4;
  size_t total = offPart + 256;
  if (ws_size < total) return;

  float* tmp = (float*)(ws + offTmp);
  float* Gall = (float*)(ws + offG);
  float* colall = (float*)(ws + offCol);
  unsigned long long* pkdall = (unsigned long long*)(ws + offPkd);
  float* hrowall = (float*)(ws + offHrow);
  unsigned* deg = (unsigned*)(ws + offDeg);
  unsigned* rowptr = (unsigned*)(ws + offRp);
  unsigned* cursor = (unsigned*)(ws + offCur);
  float* dinv = (float*)(ws + offDinv);
  int* srcs = (int*)(ws + offSrc);
  float* nrm = (float*)(ws + offNrm);
  unsigned* part = (unsigned*)(ws + offPart);

  hipMemsetAsync(ws + offG, 0, 4 * 16384 * 4 + 4 * 128 * 4 + 4 * 8, stream);
  hipMemsetAsync(ws + offDeg, 0, (size_t)N * 4, stream);

  const int EB = (E + 255) / 256;
  const int NB4 = (N + 3) / 4;
  const int GB = (N + 127) / 128;
  const int SB = (N + 1023) / 1024;
  const int SYB = 256;
  const int syrkRows = (N + SYB - 1) / SYB;

  k_deg<<<EB, 256, 0, stream>>>(edst, deg, E);
  k_scan1<<<SB, 1024, 0, stream>>>(deg, cursor, part, N);
  k_scan2<<<1, 64, 0, stream>>>(part, SB);
  k_scan3<<<SB, 1024, 0, stream>>>(deg, part, rowptr, cursor, dinv, N, SB);
  k_scatter<<<EB, 256, 0, stream>>>(esrc, edst, dinv, cursor, srcs, nrm, E);

  // encoder: h0 = x @ encW.T + encb  -> d_out
  k_gemm<<<GB, 256, 0, stream>>>(x, encW, encb, out, N);
  k_syrk_mega<<<SYB, 512, 0, stream>>>(out, Gall + 0 * 16384, colall + 0 * 128, pkdall + 0,
                                       N, syrkRows, SYB, Gall, colall, hrowall, stats_out, -1);
  k_extract<<<1, 128, 0, stream>>>(out, pkdall + 0, hrowall + 0 * 128, N);

  // layer 0
  k_gemm<<<GB, 256, 0, stream>>>(out, W0, nullptr, tmp, N);
  k_agg<true><<<NB4, 256, 0, stream>>>(tmp, rowptr, srcs, nrm, b0, out, N);
  // syrkstats(h1) + piggyback megastats(stat 0)
  k_syrk_mega<<<SYB + 1, 512, 0, stream>>>(out, Gall + 1 * 16384, colall + 1 * 128, pkdall + 1,
                                           N, syrkRows, SYB, Gall, colall, hrowall, stats_out, 0);
  k_extract<<<1, 128, 0, stream>>>(out, pkdall + 1, hrowall + 1 * 128, N);

  // layer 1
  k_gemm<<<GB, 256, 0, stream>>>(out, W1, nullptr, tmp, N);
  k_agg<true><<<NB4, 256, 0, stream>>>(tmp, rowptr, srcs, nrm, b1, out, N);
  k_syrk_mega<<<SYB + 1, 512, 0, stream>>>(out, Gall + 2 * 16384, colall + 2 * 128, pkdall + 2,
                                           N, syrkRows, SYB, Gall, colall, hrowall, stats_out, 1);
  k_extract<<<1, 128, 0, stream>>>(out, pkdall + 2, hrowall + 2 * 128, N);

  // layer 2 (no relu)
  k_gemm<<<GB, 256, 0, stream>>>(out, W2, nullptr, tmp, N);
  k_agg<false><<<NB4, 256, 0, stream>>>(tmp, rowptr, srcs, nrm, b2, out, N);
  k_syrk_mega<<<SYB + 1, 512, 0, stream>>>(out, Gall + 3 * 16384, colall + 3 * 128, pkdall + 3,
                                           N, syrkRows, SYB, Gall, colall, hrowall, stats_out, 2);
  k_extract<<<1, 128, 0, stream>>>(out, pkdall + 3, hrowall + 3 * 128, N);

  // final: megastats for stat 3 only (1 block)
  k_syrk_mega<<<1, 512, 0, stream>>>(out, Gall, colall, pkdall, N, syrkRows, 0,
                                     Gall, colall, hrowall, stats_out, 3);
}

// Round 8
// 2076.079 us; speedup vs baseline: 1.4508x; 1.4508x over previous
//
#include <hip/hip_runtime.h>
#include <hip/hip_bf16.h>

// ---------------------------------------------------------------------------
// GCN (3-layer) + encoder + rank_diff stats, all fp32.
// R8: revert R7's serializing piggyback (mega blocks run 572us EACH; in R6
//     they ran concurrently). Back to R6 schedule + fuse agg+syrkstats into
//     k_agg_syrk (2 nodes/wave float4 gather; syrk on produced tiles).
// ---------------------------------------------------------------------------

#define DIM 128

// DPP helpers: 0xB1=quad_perm xor1, 0x4E=quad_perm xor2, 0x124=row_ror:4,
// 0x128=row_ror:8, 0x142=row_bcast15, 0x143=row_bcast31.
template <int CTRL>
__device__ __forceinline__ float dpp_add(float v) {
  int x = __builtin_amdgcn_update_dpp(0, __float_as_int(v), CTRL, 0xF, 0xF, true);
  return v + __int_as_float(x);
}

// full 64-lane sum, result broadcast via readlane(63)
__device__ __forceinline__ float wave_sum(float v) {
  v = dpp_add<0xB1>(v);
  v = dpp_add<0x4E>(v);
  v = dpp_add<0x124>(v);
  v = dpp_add<0x128>(v);
  v = dpp_add<0x142>(v);
  v = dpp_add<0x143>(v);
  return __int_as_float(__builtin_amdgcn_readlane(__float_as_int(v), 63));
}

// ------------------------------- graph setup -------------------------------

__global__ void k_deg(const int* __restrict__ dst, unsigned* __restrict__ deg, int E) {
  int e = blockIdx.x * 256 + threadIdx.x;
  if (e < E) atomicAdd(&deg[dst[e]], 1u);
}

__global__ __launch_bounds__(1024) void k_scan1(const unsigned* __restrict__ deg,
                                                unsigned* __restrict__ loc,
                                                unsigned* __restrict__ part, int n) {
  __shared__ unsigned wtot[16];
  int tid = threadIdx.x, lane = tid & 63, wid = tid >> 6;
  int i = blockIdx.x * 1024 + tid;
  unsigned v = (i < n) ? deg[i] : 0u;
  unsigned s = v;
  #pragma unroll
  for (int d = 1; d < 64; d <<= 1) {
    unsigned t = __shfl_up(s, d);
    if (lane >= d) s += t;
  }
  if (lane == 63) wtot[wid] = s;
  __syncthreads();
  if (tid == 0) {
    unsigned acc = 0;
    #pragma unroll
    for (int w = 0; w < 16; w++) { unsigned t = wtot[w]; wtot[w] = acc; acc += t; }
    part[blockIdx.x] = acc;
  }
  __syncthreads();
  if (i < n) loc[i] = wtot[wid] + (s - v);
}

__global__ void k_scan2(unsigned* part, int nb) {
  int tid = threadIdx.x;  // 64 threads, nb <= 64
  unsigned v = (tid < nb) ? part[tid] : 0u;
  unsigned s = v;
  #pragma unroll
  for (int d = 1; d < 64; d <<= 1) {
    unsigned t = __shfl_up(s, d);
    if (tid >= d) s += t;
  }
  if (tid < nb) part[tid] = s - v;
  if (tid == 63) part[nb] = s;
}

__global__ __launch_bounds__(1024) void k_scan3(const unsigned* __restrict__ deg,
                                                const unsigned* __restrict__ part,
                                                unsigned* __restrict__ rowptr,
                                                unsigned* __restrict__ loc_cursor,
                                                float* __restrict__ dinv, int n, int nb) {
  int i = blockIdx.x * 1024 + threadIdx.x;
  if (i < n) {
    unsigned v = loc_cursor[i] + part[blockIdx.x];
    rowptr[i] = v;
    loc_cursor[i] = v;
    unsigned d = deg[i];
    dinv[i] = d ? 1.0f / sqrtf((float)d) : 0.0f;
  }
  if (i == 0) rowptr[n] = part[nb];
}

__global__ void k_scatter(const int* __restrict__ src, const int* __restrict__ dst,
                          const float* __restrict__ dinv, unsigned* __restrict__ cursor,
                          int* __restrict__ srcs, float* __restrict__ nrm, int E) {
  int e = blockIdx.x * 256 + threadIdx.x;
  if (e >= E) return;
  int s = src[e], d = dst[e];
  unsigned pos = atomicAdd(&cursor[d], 1u);
  srcs[pos] = s;
  nrm[pos] = dinv[s] * dinv[d];
}

// ------------------------------- GEMM: out = A @ W.T (+bias) ----------------

__global__ __launch_bounds__(256, 2) void k_gemm(const float* __restrict__ A,
                                                 const float* __restrict__ W,
                                                 const float* __restrict__ bias,
                                                 float* __restrict__ out, int M) {
  __shared__ float Hs[32][132];   // k-major: Hs[kk][row]
  __shared__ float Ws[32][132];   // k-major: Ws[kk][col]
  const int tid = threadIdx.x;
  const int r0 = blockIdx.x * 128;
  const int tx = tid & 15, ty = tid >> 4;
  const bool full = (r0 + 128 <= M);

  float acc[8][8];
  #pragma unroll
  for (int i = 0; i < 8; i++)
    #pragma unroll
    for (int j = 0; j < 8; j++) acc[i][j] = 0.f;

  #pragma unroll 1
  for (int k0 = 0; k0 < 128; k0 += 32) {
    #pragma unroll
    for (int i = 0; i < 4; i++) {
      int f4 = i * 256 + tid;
      int row = f4 >> 3, kq = f4 & 7;
      int gr = r0 + row;
      float4 v = make_float4(0.f, 0.f, 0.f, 0.f);
      if (full || gr < M) v = *(const float4*)&A[(size_t)gr * 128 + k0 + kq * 4];
      Hs[kq * 4 + 0][row] = v.x; Hs[kq * 4 + 1][row] = v.y;
      Hs[kq * 4 + 2][row] = v.z; Hs[kq * 4 + 3][row] = v.w;
    }
    #pragma unroll
    for (int i = 0; i < 4; i++) {
      int f4 = i * 256 + tid;
      int col = f4 >> 3, kq = f4 & 7;
      float4 v = *(const float4*)&W[(size_t)col * 128 + k0 + kq * 4];
      Ws[kq * 4 + 0][col] = v.x; Ws[kq * 4 + 1][col] = v.y;
      Ws[kq * 4 + 2][col] = v.z; Ws[kq * 4 + 3][col] = v.w;
    }
    __syncthreads();
    #pragma unroll 8
    for (int kk = 0; kk < 32; kk++) {
      float4 a0 = *(const float4*)&Hs[kk][ty * 8];
      float4 a1 = *(const float4*)&Hs[kk][ty * 8 + 4];
      float4 b0 = *(const float4*)&Ws[kk][tx * 8];
      float4 b1 = *(const float4*)&Ws[kk][tx * 8 + 4];
      float a[8] = { a0.x, a0.y, a0.z, a0.w, a1.x, a1.y, a1.z, a1.w };
      float b[8] = { b0.x, b0.y, b0.z, b0.w, b1.x, b1.y, b1.z, b1.w };
      #pragma unroll
      for (int i = 0; i < 8; i++)
        #pragma unroll
        for (int j = 0; j < 8; j++) acc[i][j] += a[i] * b[j];
    }
    __syncthreads();
  }

  float bb[8] = {0.f,0.f,0.f,0.f,0.f,0.f,0.f,0.f};
  if (bias) {
    float4 v0 = *(const float4*)&bias[tx * 8];
    float4 v1 = *(const float4*)&bias[tx * 8 + 4];
    bb[0]=v0.x; bb[1]=v0.y; bb[2]=v0.z; bb[3]=v0.w;
    bb[4]=v1.x; bb[5]=v1.y; bb[6]=v1.z; bb[7]=v1.w;
  }
  #pragma unroll
  for (int i = 0; i < 8; i++) {
    int gr = r0 + ty * 8 + i;
    if (full || gr < M) {
      float4 o0 = make_float4(acc[i][0]+bb[0], acc[i][1]+bb[1], acc[i][2]+bb[2], acc[i][3]+bb[3]);
      float4 o1 = make_float4(acc[i][4]+bb[4], acc[i][5]+bb[5], acc[i][6]+bb[6], acc[i][7]+bb[7]);
      *(float4*)&out[(size_t)gr * 128 + tx * 8] = o0;
      *(float4*)&out[(size_t)gr * 128 + tx * 8 + 4] = o1;
    }
  }
}

// --------------------- SYRK + row/col stats (encoder layer) ----------------

__global__ __launch_bounds__(256) void k_syrkstats(const float* __restrict__ h,
                                                   float* __restrict__ G,
                                                   float* __restrict__ colsum,
                                                   unsigned long long* __restrict__ packed,
                                                   int N, int rowsPer) {
  __shared__ float hs[8][132];
  __shared__ float csS[128];
  __shared__ unsigned long long pkS[8];
  int tid = threadIdx.x;
  int tx = tid & 15, ty = tid >> 4;
  int rr = tid >> 5, c4 = (tid & 31) * 4;
  float acc[8][8];
  #pragma unroll
  for (int i = 0; i < 8; i++)
    #pragma unroll
    for (int j = 0; j < 8; j++) acc[i][j] = 0.f;
  float ca0 = 0.f, ca1 = 0.f, ca2 = 0.f, ca3 = 0.f;
  unsigned long long best = 0;
  if (tid < 128) csS[tid] = 0.f;
  __syncthreads();

  int rstart = blockIdx.x * rowsPer;
  int rend = rstart + rowsPer;
  if (rend > N) rend = N;
  for (int rb = rstart; rb < rend; rb += 8) {
    int gr = rb + rr;
    float4 v = make_float4(0.f, 0.f, 0.f, 0.f);
    if (gr < rend) v = *(const float4*)&h[(size_t)gr * 128 + c4];
    __syncthreads();
    *(float4*)&hs[rr][c4] = v;
    float avx = fabsf(v.x), avy = fabsf(v.y), avz = fabsf(v.z), avw = fabsf(v.w);
    ca0 += avx; ca1 += avy; ca2 += avz; ca3 += avw;
    float rs = (avx + avy) + (avz + avw);
    rs = dpp_add<0xB1>(rs);
    rs = dpp_add<0x4E>(rs);
    rs = dpp_add<0x124>(rs);
    rs = dpp_add<0x128>(rs);
    rs = dpp_add<0x142>(rs);  // lanes 16-31 / 48-63 hold full 32-lane row sums
    if (gr < rend) {
      unsigned long long pk = ((unsigned long long)__float_as_uint(rs) << 32)
                            | (unsigned long long)(0xFFFFFFFFu - (unsigned)gr);
      if (pk > best) best = pk;
    }
    __syncthreads();
    #pragma unroll
    for (int r2 = 0; r2 < 8; r2++) {
      float4 a0 = *(const float4*)&hs[r2][ty * 8];
      float4 a1 = *(const float4*)&hs[r2][ty * 8 + 4];
      float4 b0 = *(const float4*)&hs[r2][tx * 8];
      float4 b1 = *(const float4*)&hs[r2][tx * 8 + 4];
      float a[8] = { a0.x,a0.y,a0.z,a0.w,a1.x,a1.y,a1.z,a1.w };
      float b[8] = { b0.x,b0.y,b0.z,b0.w,b1.x,b1.y,b1.z,b1.w };
      #pragma unroll
      for (int i = 0; i < 8; i++)
        #pragma unroll
        for (int j = 0; j < 8; j++) acc[i][j] += a[i] * b[j];
    }
  }
  if ((tid & 31) == 16) pkS[tid >> 5] = best;
  atomicAdd(&csS[c4 + 0], ca0);
  atomicAdd(&csS[c4 + 1], ca1);
  atomicAdd(&csS[c4 + 2], ca2);
  atomicAdd(&csS[c4 + 3], ca3);
  __syncthreads();
  if (tid == 0) {
    unsigned long long m = pkS[0];
    #pragma unroll
    for (int w = 1; w < 8; w++) if (pkS[w] > m) m = pkS[w];
    atomicMax(packed, m);
  }
  if (tid < 128) atomicAdd(&colsum[tid], csS[tid]);
  #pragma unroll
  for (int i = 0; i < 8; i++)
    #pragma unroll
    for (int j = 0; j < 8; j++)
      atomicAdd(&G[(size_t)(ty * 8 + i) * 128 + tx * 8 + j], acc[i][j]);
}

// -------- fused aggregation + bias/relu + SYRK + row/col stats --------------
// Each block owns rowsPer consecutive dst nodes. Tiles of 8 nodes: each wave
// gathers 2 nodes (32-lane halves, float4/lane), writes out + LDS, then
// syrk-accumulates the tile. Saves re-reading out from HBM/L3 + a launch.

template <bool RELU>
__global__ __launch_bounds__(256) void k_agg_syrk(const float* __restrict__ tmp,
                                                  const unsigned* __restrict__ rowptr,
                                                  const int* __restrict__ srcs,
                                                  const float* __restrict__ nrm,
                                                  const float* __restrict__ bias,
                                                  float* __restrict__ out,
                                                  float* __restrict__ G,
                                                  float* __restrict__ colsum,
                                                  unsigned long long* __restrict__ packed,
                                                  int N, int rowsPer) {
  __shared__ float hs[8][132];
  __shared__ float csS[128];
  __shared__ unsigned long long pkS[8];
  const int tid = threadIdx.x;
  const int wid = tid >> 6, lane = tid & 63;
  const int half = lane >> 5;            // 0/1: which node of this wave
  const int c4 = (lane & 31) * 4;        // this lane's 4 columns
  const int tx = tid & 15, ty = tid >> 4;
  const int lr = wid * 2 + half;         // row 0..7 within tile

  float acc[8][8];
  #pragma unroll
  for (int i = 0; i < 8; i++)
    #pragma unroll
    for (int j = 0; j < 8; j++) acc[i][j] = 0.f;
  float ca0 = 0.f, ca1 = 0.f, ca2 = 0.f, ca3 = 0.f;
  unsigned long long best = 0;
  if (tid < 128) csS[tid] = 0.f;

  const float4 bv = *(const float4*)&bias[c4];
  int rstart = blockIdx.x * rowsPer;
  int rend = rstart + rowsPer;
  if (rend > N) rend = N;
  __syncthreads();

  for (int rb = rstart; rb < rend; rb += 8) {
    int node = rb + lr;
    float4 a = make_float4(0.f, 0.f, 0.f, 0.f);
    if (node < rend) {
      unsigned e = rowptr[node], e1 = rowptr[node + 1];
      for (; e < e1; ++e) {
        int s = srcs[e];
        float w = nrm[e];
        float4 x = *(const float4*)&tmp[(size_t)s * 128 + c4];
        a.x += w * x.x; a.y += w * x.y; a.z += w * x.z; a.w += w * x.w;
      }
      a.x += bv.x; a.y += bv.y; a.z += bv.z; a.w += bv.w;
      if (RELU) {
        a.x = fmaxf(a.x, 0.f); a.y = fmaxf(a.y, 0.f);
        a.z = fmaxf(a.z, 0.f); a.w = fmaxf(a.w, 0.f);
      }
      *(float4*)&out[(size_t)node * 128 + c4] = a;
    }
    __syncthreads();   // previous tile's hs readers done
    *(float4*)&hs[lr][c4] = a;   // zeros for node >= rend
    // row/col stats on produced tile
    float avx = fabsf(a.x), avy = fabsf(a.y), avz = fabsf(a.z), avw = fabsf(a.w);
    ca0 += avx; ca1 += avy; ca2 += avz; ca3 += avw;
    float rs = (avx + avy) + (avz + avw);
    rs = dpp_add<0xB1>(rs);
    rs = dpp_add<0x4E>(rs);
    rs = dpp_add<0x124>(rs);
    rs = dpp_add<0x128>(rs);
    rs = dpp_add<0x142>(rs);  // lanes 16-31 / 48-63 hold their half's row sum
    if (node < rend) {
      unsigned long long pk = ((unsigned long long)__float_as_uint(rs) << 32)
                            | (unsigned long long)(0xFFFFFFFFu - (unsigned)node);
      if (pk > best) best = pk;
    }
    __syncthreads();
    #pragma unroll
    for (int r2 = 0; r2 < 8; r2++) {
      float4 a0 = *(const float4*)&hs[r2][ty * 8];
      float4 a1 = *(const float4*)&hs[r2][ty * 8 + 4];
      float4 b0 = *(const float4*)&hs[r2][tx * 8];
      float4 b1 = *(const float4*)&hs[r2][tx * 8 + 4];
      float aa[8] = { a0.x,a0.y,a0.z,a0.w,a1.x,a1.y,a1.z,a1.w };
      float bb[8] = { b0.x,b0.y,b0.z,b0.w,b1.x,b1.y,b1.z,b1.w };
      #pragma unroll
      for (int i = 0; i < 8; i++)
        #pragma unroll
        for (int j = 0; j < 8; j++) acc[i][j] += aa[i] * bb[j];
    }
  }
  if ((lane & 31) == 16) pkS[lr] = best;
  atomicAdd(&csS[c4 + 0], ca0);
  atomicAdd(&csS[c4 + 1], ca1);
  atomicAdd(&csS[c4 + 2], ca2);
  atomicAdd(&csS[c4 + 3], ca3);
  __syncthreads();
  if (tid == 0) {
    unsigned long long m = pkS[0];
    #pragma unroll
    for (int w = 1; w < 8; w++) if (pkS[w] > m) m = pkS[w];
    atomicMax(packed, m);
  }
  if (tid < 128) atomicAdd(&colsum[tid], csS[tid]);
  #pragma unroll
  for (int i = 0; i < 8; i++)
    #pragma unroll
    for (int j = 0; j < 8; j++)
      atomicAdd(&G[(size_t)(ty * 8 + i) * 128 + tx * 8 + j], acc[i][j]);
}

__global__ void k_extract(const float* __restrict__ h,
                          const unsigned long long* __restrict__ packed,
                          float* __restrict__ hrow, int N) {
  unsigned long long pk = *packed;
  unsigned i = 0xFFFFFFFFu - (unsigned)(pk & 0xFFFFFFFFull);
  if (i >= (unsigned)N) i = 0;
  hrow[threadIdx.x] = h[(size_t)i * 128 + threadIdx.x];
}

// ------------------------------- megastats (R6 verbatim) -------------------

__global__ __launch_bounds__(512) void k_megastats4(const float* __restrict__ Gall,
                                                    const float* __restrict__ colall,
                                                    const float* __restrict__ hrowall,
                                                    float* __restrict__ outstats) {
  const int blk = blockIdx.x;
  const float* G = Gall + (size_t)blk * 16384;
  const float* colsum = colall + blk * 128;
  const float* hrowg = hrowall + blk * 128;

  __shared__ __align__(16) float colk[128];
  __shared__ __align__(16) float wwF[256];    // ww[2][128] double buffer
  __shared__ __align__(16) float lamp[8];
  __shared__ float sigp[2];
  __shared__ float diag[128], offd[128];
  __shared__ float asS[128], b2S[128];
  __shared__ float loS[128], hiS[128];
  __shared__ float hiRow[128], gjS[128];
  __shared__ int cntS[512];
  __shared__ float redw[8];
  __shared__ float scal[16];
  __shared__ int ishared[4];

  const int tid = threadIdx.x;
  const int lane = tid & 63;
  const int wv = tid >> 6;     // wave 0..7
  const int q = tid >> 7;      // slice 0..3 (wave-pair)
  const int r = tid & 127;     // row
  const int cbase = q * 32;
  float Areg[32];

  #pragma unroll
  for (int cc = 0; cc < 32; cc++) {
    int c = cbase + cc;
    Areg[cc] = 0.5f * (G[(size_t)r * 128 + c] + G[(size_t)c * 128 + r]);
  }

  for (int solve = 0; solve < 2; solve++) {
    if (q == 0) colk[r] = (r == 0) ? 0.f : Areg[0];
    if (tid == 0) diag[0] = Areg[0];
    if (tid < 256) wwF[tid] = 0.f;
    if (q == 0) {
      float m2 = (r >= 1) ? Areg[0] * Areg[0] : 0.f;
      float s = wave_sum(m2);
      if (lane == 0) sigp[wv] = s;   // wv = 0,1
    }
    __syncthreads();

    for (int k = 0; k <= 125; k++) {
      const int kp1 = k + 1;
      float* wwc = &wwF[(k & 1) * 128];
      float* wwn = &wwF[(1 - (k & 1)) * 128];
      // ---- phase A ----
      float sig = sigp[0] + sigp[1];
      float xk1 = colk[kp1];
      float nx = sqrtf(sig);
      float alpha = (xk1 >= 0.f) ? -nx : nx;
      float vns = 2.0f * (sig - alpha * xk1);
      float rvn = (vns > 1e-35f) ? rsqrtf(vns) : 0.f;
      float narvn = -alpha * rvn;
      float ckr = colk[r];
      float vr = ckr * rvn + ((r == kp1) ? narvn : 0.f);
      const bool act = (cbase + 31 >= k);
      float4 cv[8];
      float p = 0.f;
      if (act) {
        const float4* cp = (const float4*)&colk[cbase];  // broadcast reads
        #pragma unroll
        for (int i = 0; i < 8; i++) cv[i] = cp[i];
        if (r >= k) {
          #pragma unroll
          for (int i = 0; i < 8; i++)
            p += Areg[4*i+0]*cv[i].x + Areg[4*i+1]*cv[i].y
               + Areg[4*i+2]*cv[i].z + Areg[4*i+3]*cv[i].w;
          int kl = kp1 - cbase;
          float akp1 = 0.f;
          if (kl >= 0 && kl < 32) {
            #pragma unroll
            for (int i = 0; i < 32; i++) if (i == kl) akp1 = Areg[i];
          }
          p = rvn * p + narvn * akp1;
          atomicAdd(&wwc[r], p);      // ds_add_f32, cross-wave combine
        }
      }
      float lp = vr * p;
      float ls = wave_sum(lp);
      if (lane == 0) lamp[wv] = ls;
      if (tid == 0) offd[k] = alpha;
      __syncthreads();

      // ---- phase B ----
      float4 l0 = *(const float4*)&lamp[0];
      float4 l1 = *(const float4*)&lamp[4];
      float lam = ((l0.x + l0.y) + (l0.z + l0.w)) + ((l1.x + l1.y) + (l1.z + l1.w));
      const int qo = kp1 >> 5;
      float nextc = 0.f;
      if (act && r >= k) {
        float wr = wwc[r];
        float qr = 2.0f * (wr - lam * vr);
        const int kl = kp1 - cbase;
        const float4* wp = (const float4*)&wwc[cbase];   // broadcast reads
        #pragma unroll
        for (int i = 0; i < 8; i++) {
          const int c0 = 4 * i;
          float4 wc = wp[i];
          float v0 = cv[i].x * rvn + ((c0 + 0 == kl) ? narvn : 0.f);
          float v1 = cv[i].y * rvn + ((c0 + 1 == kl) ? narvn : 0.f);
          float v2 = cv[i].z * rvn + ((c0 + 2 == kl) ? narvn : 0.f);
          float v3 = cv[i].w * rvn + ((c0 + 3 == kl) ? narvn : 0.f);
          float q0 = 2.f * (wc.x - lam * v0);
          float q1 = 2.f * (wc.y - lam * v1);
          float q2 = 2.f * (wc.z - lam * v2);
          float q3 = 2.f * (wc.w - lam * v3);
          float a0 = Areg[c0+0] - (vr * q0 + qr * v0); Areg[c0+0] = a0;
          float a1 = Areg[c0+1] - (vr * q1 + qr * v1); Areg[c0+1] = a1;
          float a2 = Areg[c0+2] - (vr * q2 + qr * v2); Areg[c0+2] = a2;
          float a3 = Areg[c0+3] - (vr * q3 + qr * v3); Areg[c0+3] = a3;
          if (c0 + 0 == kl) nextc = a0;
          if (c0 + 1 == kl) nextc = a1;
          if (c0 + 2 == kl) nextc = a2;
          if (c0 + 3 == kl) nextc = a3;
        }
      }
      if (q == qo && r >= k) colk[r] = (r <= kp1) ? 0.f : nextc;
      if (q == qo && r == kp1) diag[kp1] = nextc;
      if (q == qo) {
        float m2 = (r > kp1 && r >= k) ? nextc * nextc : 0.f;
        float s = wave_sum(m2);
        if (lane == 0) sigp[wv & 1] = s;
      }
      if (q == 1) wwn[r] = 0.f;   // zero next buffer
      __syncthreads();
    }
    if (tid == 0) offd[126] = colk[127];
    if (q == 3 && r == 127) diag[127] = Areg[31];
    __syncthreads();

    // ---- Gershgorin bound ----
    if (tid < 128) {
      float t = fabsf(diag[tid]);
      if (tid > 0) t += fabsf(offd[tid - 1]);
      if (tid < 127) t += fabsf(offd[tid]);
      #pragma unroll
      for (int m = 32; m >= 1; m >>= 1) t = fmaxf(t, __shfl_xor(t, m));
      if (lane == 0) redw[wv] = t;
    }
    __syncthreads();
    if (tid == 0) {
      float g = fmaxf(redw[0], redw[1]);
      if (!(g > 1e-30f)) g = 1.f;
      scal[3] = g; scal[5] = 1.0f / g;
    }
    __syncthreads();
    if (tid < 128) {
      float ginv = scal[5];
      asS[tid] = diag[tid] * ginv;
      float ob = (tid < 127) ? offd[tid] * ginv : 0.f;
      b2S[tid] = ob * ob;
      loS[tid] = -0.0625f;
      hiS[tid] = 1.03125f;
    }
    __syncthreads();

    // ---- multisection bisection ----
    for (int round = 0; round < 12; round++) {
      int kk = tid & 127;
      int t = tid >> 7;
      float l = loS[kk], h2v = hiS[kk];
      float sigma = l + (h2v - l) * 0.2f * (float)(t + 1);
      const float PIV = 1e-20f;
      float d = asS[0] - sigma;
      if (fabsf(d) < PIV) d = -PIV;
      int cnt = (d < 0.f) ? 1 : 0;
      for (int i = 1; i < 128; i++) {
        d = (asS[i] - sigma) - b2S[i - 1] * __builtin_amdgcn_rcpf(d);
        if (fabsf(d) < PIV) d = -PIV;
        cnt += (d < 0.f) ? 1 : 0;
      }
      cntS[tid] = cnt;
      __syncthreads();
      if (tid < 128) {
        int c0 = cntS[tid], c1 = cntS[tid + 128], c2 = cntS[tid + 256], c3 = cntS[tid + 384];
        float l2 = loS[tid], h2 = hiS[tid];
        float w = (h2 - l2) * 0.2f;
        int cross = 4;
        if (c0 > tid) cross = 0;
        else if (c1 > tid) cross = 1;
        else if (c2 > tid) cross = 2;
        else if (c3 > tid) cross = 3;
        loS[tid] = (cross == 0) ? l2 : l2 + w * (float)cross;
        hiS[tid] = (cross == 4) ? h2 : l2 + w * (float)(cross + 1);
      }
      __syncthreads();
    }
    // ---- sum sqrt eigenvalues ----
    if (tid < 128) {
      float lam2 = 0.5f * (loS[tid] + hiS[tid]);
      lam2 = fmaxf(lam2, 0.f) * scal[3];
      float s = sqrtf(lam2);
      #pragma unroll
      for (int m = 32; m >= 1; m >>= 1) s += __shfl_xor(s, m);
      if (lane == 0) redw[wv] = s;
    }
    __syncthreads();
    if (tid == 0) scal[4] = redw[0] + redw[1];
    __syncthreads();

    if (solve == 0) {
      if (tid < 128) hiRow[tid] = hrowg[tid];
      __syncthreads();
      if (tid < 128) {
        float v = colsum[tid];
        int idx = tid;
        #pragma unroll
        for (int m = 32; m >= 1; m >>= 1) {
          float v2 = __shfl_xor(v, m);
          int i2 = __shfl_xor(idx, m);
          if (v2 > v || (v2 == v && i2 < idx)) { v = v2; idx = i2; }
        }
        if (lane == 0) { redw[wv] = v; ishared[wv] = idx; }
        float hv = hiRow[tid];
        float nh = hv * hv;
        #pragma unroll
        for (int m = 32; m >= 1; m >>= 1) nh += __shfl_xor(nh, m);
        if (lane == 0) redw[4 + wv] = nh;
      }
      __syncthreads();
      if (tid == 0) {
        float v0 = redw[0], v1 = redw[1];
        int j = (v1 > v0 || (v1 == v0 && ishared[1] < ishared[0])) ? ishared[1] : ishared[0];
        float nh2 = redw[4] + redw[5];
        float nu = scal[4];
        float Gjj = G[(size_t)j * 128 + j];
        float hij = hiRow[j];
        float sflip = (hij < 0.f) ? -1.f : 1.f;
        scal[6] = 1.0f / (nu * nu);
        scal[7] = sflip / (nu * sqrtf(Gjj) * sqrtf(nh2));
        scal[8] = 1.0f / nh2;
        ishared[2] = j;
      }
      __syncthreads();
      int j = ishared[2];
      if (tid < 128) gjS[tid] = 0.5f * (G[(size_t)tid * 128 + j] + G[(size_t)j * 128 + tid]);
      __syncthreads();
      float inv2 = scal[6], c1 = scal[7], c2 = scal[8];
      float gr_ = gjS[r], hr_ = hiRow[r];
      #pragma unroll
      for (int cc = 0; cc < 32; cc++) {
        int c = cbase + cc;
        float gsym = 0.5f * (G[(size_t)r * 128 + c] + G[(size_t)c * 128 + r]);
        Areg[cc] = gsym * inv2 - c1 * (gr_ * hiRow[c] + hr_ * gjS[c]) + c2 * hr_ * hiRow[c];
      }
      __syncthreads();
    }
  }
  if (tid == 0) outstats[blk] = scal[4];
}

// ------------------------------- host driver -------------------------------

extern "C" void kernel_launch(void* const* d_in, const int* in_sizes, int n_in,
                              void* d_out, int out_size, void* d_ws, size_t ws_size,
                              hipStream_t stream) {
  const float* x = (const float*)d_in[0];
  const int* edge = (const int*)d_in[1];
  const float* encW = (const float*)d_in[2];
  const float* encb = (const float*)d_in[3];
  const float* W0 = (const float*)d_in[4];
  const float* b0 = (const float*)d_in[5];
  const float* W1 = (const float*)d_in[6];
  const float* b1 = (const float*)d_in[7];
  const float* W2 = (const float*)d_in[8];
  const float* b2 = (const float*)d_in[9];

  const int N = in_sizes[0] / 128;
  const int E = in_sizes[1] / 2;
  const int* esrc = edge;
  const int* edst = edge + E;

  float* out = (float*)d_out;
  float* stats_out = out + (size_t)N * 128;

  char* ws = (char*)d_ws;
  size_t offTmp = 0;
  size_t offG = offTmp + (size_t)N * 128 * 4;
  size_t offCol = offG + 4 * 16384 * 4;
  size_t offPkd = offCol + 4 * 128 * 4;
  size_t offHrow = offPkd + 4 * 8;
  size_t offDeg = offHrow + 4 * 128 * 4;
  size_t offRp = offDeg + (size_t)N * 4;
  size_t offCur = offRp + (size_t)(N + 1) * 4;
  size_t offDinv = offCur + (size_t)N * 4;
  size_t offSrc = offDinv + (size_t)N * 4;
  size_t offNrm = offSrc + (size_t)E * 4;
  size_t offPart = offNrm + (size_t)E * 4;
  size_t total = offPart + 256;
  if (ws_size < total) return;

  float* tmp = (float*)(ws + offTmp);
  float* Gall = (float*)(ws + offG);
  float* colall = (float*)(ws + offCol);
  unsigned long long* pkdall = (unsigned long long*)(ws + offPkd);
  float* hrowall = (float*)(ws + offHrow);
  unsigned* deg = (unsigned*)(ws + offDeg);
  unsigned* rowptr = (unsigned*)(ws + offRp);
  unsigned* cursor = (unsigned*)(ws + offCur);
  float* dinv = (float*)(ws + offDinv);
  int* srcs = (int*)(ws + offSrc);
  float* nrm = (float*)(ws + offNrm);
  unsigned* part = (unsigned*)(ws + offPart);

  hipMemsetAsync(ws + offG, 0, 4 * 16384 * 4 + 4 * 128 * 4 + 4 * 8, stream);
  hipMemsetAsync(ws + offDeg, 0, (size_t)N * 4, stream);

  const int EB = (E + 255) / 256;
  const int GB = (N + 127) / 128;
  const int SB = (N + 1023) / 1024;
  const int SYB = 256;
  const int syrkRows = (N + SYB - 1) / SYB;

  k_deg<<<EB, 256, 0, stream>>>(edst, deg, E);
  k_scan1<<<SB, 1024, 0, stream>>>(deg, cursor, part, N);
  k_scan2<<<1, 64, 0, stream>>>(part, SB);
  k_scan3<<<SB, 1024, 0, stream>>>(deg, part, rowptr, cursor, dinv, N, SB);
  k_scatter<<<EB, 256, 0, stream>>>(esrc, edst, dinv, cursor, srcs, nrm, E);

  // encoder: h0 = x @ encW.T + encb  -> d_out
  k_gemm<<<GB, 256, 0, stream>>>(x, encW, encb, out, N);
  k_syrkstats<<<SYB, 256, 0, stream>>>(out, Gall + 0 * 16384, colall + 0 * 128, pkdall + 0, N, syrkRows);
  k_extract<<<1, 128, 0, stream>>>(out, pkdall + 0, hrowall + 0 * 128, N);

  // layer 0
  k_gemm<<<GB, 256, 0, stream>>>(out, W0, nullptr, tmp, N);
  k_agg_syrk<true><<<SYB, 256, 0, stream>>>(tmp, rowptr, srcs, nrm, b0, out,
                                            Gall + 1 * 16384, colall + 1 * 128, pkdall + 1, N, syrkRows);
  k_extract<<<1, 128, 0, stream>>>(out, pkdall + 1, hrowall + 1 * 128, N);

  // layer 1
  k_gemm<<<GB, 256, 0, stream>>>(out, W1, nullptr, tmp, N);
  k_agg_syrk<true><<<SYB, 256, 0, stream>>>(tmp, rowptr, srcs, nrm, b1, out,
                                            Gall + 2 * 16384, colall + 2 * 128, pkdall + 2, N, syrkRows);
  k_extract<<<1, 128, 0, stream>>>(out, pkdall + 2, hrowall + 2 * 128, N);

  // layer 2 (no relu)
  k_gemm<<<GB, 256, 0, stream>>>(out, W2, nullptr, tmp, N);
  k_agg_syrk<false><<<SYB, 256, 0, stream>>>(tmp, rowptr, srcs, nrm, b2, out,
                                             Gall + 3 * 16384, colall + 3 * 128, pkdall + 3, N, syrkRows);
  k_extract<<<1, 128, 0, stream>>>(out, pkdall + 3, hrowall + 3 * 128, N);

  // all four stats concurrently (4 blocks on 4 CUs)
  k_megastats4<<<4, 512, 0, stream>>>(Gall, colall, hrowall, stats_out);
}

// Round 9
// 1854.478 us; speedup vs baseline: 1.6242x; 1.1195x over previous
//
#include <hip/hip_runtime.h>
#include <hip/hip_bf16.h>

// ---------------------------------------------------------------------------
// GCN (3-layer) + encoder + rank_diff stats, all fp32.
// R9: revert R8's agg+syrk fusion (killed gather TLP: 12500->256 blocks).
//     Megastats at 1024 threads (8-way column slices, 16 cols/thread):
//     halves dependent chains, 2x waves/SIMD for latency hiding.
// ---------------------------------------------------------------------------

#define DIM 128

// DPP helpers
template <int CTRL>
__device__ __forceinline__ float dpp_add(float v) {
  int x = __builtin_amdgcn_update_dpp(0, __float_as_int(v), CTRL, 0xF, 0xF, true);
  return v + __int_as_float(x);
}

// full 64-lane sum, result broadcast via readlane(63)
__device__ __forceinline__ float wave_sum(float v) {
  v = dpp_add<0xB1>(v);
  v = dpp_add<0x4E>(v);
  v = dpp_add<0x124>(v);
  v = dpp_add<0x128>(v);
  v = dpp_add<0x142>(v);
  v = dpp_add<0x143>(v);
  return __int_as_float(__builtin_amdgcn_readlane(__float_as_int(v), 63));
}

// ------------------------------- graph setup -------------------------------

__global__ void k_deg(const int* __restrict__ dst, unsigned* __restrict__ deg, int E) {
  int e = blockIdx.x * 256 + threadIdx.x;
  if (e < E) atomicAdd(&deg[dst[e]], 1u);
}

__global__ __launch_bounds__(1024) void k_scan1(const unsigned* __restrict__ deg,
                                                unsigned* __restrict__ loc,
                                                unsigned* __restrict__ part, int n) {
  __shared__ unsigned wtot[16];
  int tid = threadIdx.x, lane = tid & 63, wid = tid >> 6;
  int i = blockIdx.x * 1024 + tid;
  unsigned v = (i < n) ? deg[i] : 0u;
  unsigned s = v;
  #pragma unroll
  for (int d = 1; d < 64; d <<= 1) {
    unsigned t = __shfl_up(s, d);
    if (lane >= d) s += t;
  }
  if (lane == 63) wtot[wid] = s;
  __syncthreads();
  if (tid == 0) {
    unsigned acc = 0;
    #pragma unroll
    for (int w = 0; w < 16; w++) { unsigned t = wtot[w]; wtot[w] = acc; acc += t; }
    part[blockIdx.x] = acc;
  }
  __syncthreads();
  if (i < n) loc[i] = wtot[wid] + (s - v);
}

__global__ void k_scan2(unsigned* part, int nb) {
  int tid = threadIdx.x;  // 64 threads, nb <= 64
  unsigned v = (tid < nb) ? part[tid] : 0u;
  unsigned s = v;
  #pragma unroll
  for (int d = 1; d < 64; d <<= 1) {
    unsigned t = __shfl_up(s, d);
    if (tid >= d) s += t;
  }
  if (tid < nb) part[tid] = s - v;
  if (tid == 63) part[nb] = s;
}

__global__ __launch_bounds__(1024) void k_scan3(const unsigned* __restrict__ deg,
                                                const unsigned* __restrict__ part,
                                                unsigned* __restrict__ rowptr,
                                                unsigned* __restrict__ loc_cursor,
                                                float* __restrict__ dinv, int n, int nb) {
  int i = blockIdx.x * 1024 + threadIdx.x;
  if (i < n) {
    unsigned v = loc_cursor[i] + part[blockIdx.x];
    rowptr[i] = v;
    loc_cursor[i] = v;
    unsigned d = deg[i];
    dinv[i] = d ? 1.0f / sqrtf((float)d) : 0.0f;
  }
  if (i == 0) rowptr[n] = part[nb];
}

__global__ void k_scatter(const int* __restrict__ src, const int* __restrict__ dst,
                          const float* __restrict__ dinv, unsigned* __restrict__ cursor,
                          int* __restrict__ srcs, float* __restrict__ nrm, int E) {
  int e = blockIdx.x * 256 + threadIdx.x;
  if (e >= E) return;
  int s = src[e], d = dst[e];
  unsigned pos = atomicAdd(&cursor[d], 1u);
  srcs[pos] = s;
  nrm[pos] = dinv[s] * dinv[d];
}

// ------------------------------- GEMM: out = A @ W.T (+bias) ----------------

__global__ __launch_bounds__(256, 2) void k_gemm(const float* __restrict__ A,
                                                 const float* __restrict__ W,
                                                 const float* __restrict__ bias,
                                                 float* __restrict__ out, int M) {
  __shared__ float Hs[32][132];   // k-major: Hs[kk][row]
  __shared__ float Ws[32][132];   // k-major: Ws[kk][col]
  const int tid = threadIdx.x;
  const int r0 = blockIdx.x * 128;
  const int tx = tid & 15, ty = tid >> 4;
  const bool full = (r0 + 128 <= M);

  float acc[8][8];
  #pragma unroll
  for (int i = 0; i < 8; i++)
    #pragma unroll
    for (int j = 0; j < 8; j++) acc[i][j] = 0.f;

  #pragma unroll 1
  for (int k0 = 0; k0 < 128; k0 += 32) {
    #pragma unroll
    for (int i = 0; i < 4; i++) {
      int f4 = i * 256 + tid;
      int row = f4 >> 3, kq = f4 & 7;
      int gr = r0 + row;
      float4 v = make_float4(0.f, 0.f, 0.f, 0.f);
      if (full || gr < M) v = *(const float4*)&A[(size_t)gr * 128 + k0 + kq * 4];
      Hs[kq * 4 + 0][row] = v.x; Hs[kq * 4 + 1][row] = v.y;
      Hs[kq * 4 + 2][row] = v.z; Hs[kq * 4 + 3][row] = v.w;
    }
    #pragma unroll
    for (int i = 0; i < 4; i++) {
      int f4 = i * 256 + tid;
      int col = f4 >> 3, kq = f4 & 7;
      float4 v = *(const float4*)&W[(size_t)col * 128 + k0 + kq * 4];
      Ws[kq * 4 + 0][col] = v.x; Ws[kq * 4 + 1][col] = v.y;
      Ws[kq * 4 + 2][col] = v.z; Ws[kq * 4 + 3][col] = v.w;
    }
    __syncthreads();
    #pragma unroll 8
    for (int kk = 0; kk < 32; kk++) {
      float4 a0 = *(const float4*)&Hs[kk][ty * 8];
      float4 a1 = *(const float4*)&Hs[kk][ty * 8 + 4];
      float4 b0 = *(const float4*)&Ws[kk][tx * 8];
      float4 b1 = *(const float4*)&Ws[kk][tx * 8 + 4];
      float a[8] = { a0.x, a0.y, a0.z, a0.w, a1.x, a1.y, a1.z, a1.w };
      float b[8] = { b0.x, b0.y, b0.z, b0.w, b1.x, b1.y, b1.z, b1.w };
      #pragma unroll
      for (int i = 0; i < 8; i++)
        #pragma unroll
        for (int j = 0; j < 8; j++) acc[i][j] += a[i] * b[j];
    }
    __syncthreads();
  }

  float bb[8] = {0.f,0.f,0.f,0.f,0.f,0.f,0.f,0.f};
  if (bias) {
    float4 v0 = *(const float4*)&bias[tx * 8];
    float4 v1 = *(const float4*)&bias[tx * 8 + 4];
    bb[0]=v0.x; bb[1]=v0.y; bb[2]=v0.z; bb[3]=v0.w;
    bb[4]=v1.x; bb[5]=v1.y; bb[6]=v1.z; bb[7]=v1.w;
  }
  #pragma unroll
  for (int i = 0; i < 8; i++) {
    int gr = r0 + ty * 8 + i;
    if (full || gr < M) {
      float4 o0 = make_float4(acc[i][0]+bb[0], acc[i][1]+bb[1], acc[i][2]+bb[2], acc[i][3]+bb[3]);
      float4 o1 = make_float4(acc[i][4]+bb[4], acc[i][5]+bb[5], acc[i][6]+bb[6], acc[i][7]+bb[7]);
      *(float4*)&out[(size_t)gr * 128 + tx * 8] = o0;
      *(float4*)&out[(size_t)gr * 128 + tx * 8 + 4] = o1;
    }
  }
}

// ------------------------------- aggregation (R6) --------------------------

template <bool RELU>
__global__ __launch_bounds__(256) void k_agg(const float* __restrict__ tmp,
                                             const unsigned* __restrict__ rowptr,
                                             const int* __restrict__ srcs,
                                             const float* __restrict__ nrm,
                                             const float* __restrict__ bias,
                                             float* __restrict__ out, int N) {
  int wid = threadIdx.x >> 6, lane = threadIdx.x & 63;
  int n = blockIdx.x * 4 + wid;
  if (n >= N) return;
  unsigned e0 = rowptr[n], e1 = rowptr[n + 1];
  float ax = 0.f, ay = 0.f;
  unsigned e = e0;
  for (; e + 2 <= e1; e += 2) {
    int s0 = srcs[e], s1 = srcs[e + 1];
    float w0 = nrm[e], w1 = nrm[e + 1];
    float2 x0 = *(const float2*)&tmp[(size_t)s0 * 128 + 2 * lane];
    float2 x1 = *(const float2*)&tmp[(size_t)s1 * 128 + 2 * lane];
    ax += w0 * x0.x + w1 * x1.x;
    ay += w0 * x0.y + w1 * x1.y;
  }
  if (e < e1) {
    int s = srcs[e];
    float w = nrm[e];
    float2 x0 = *(const float2*)&tmp[(size_t)s * 128 + 2 * lane];
    ax += w * x0.x;
    ay += w * x0.y;
  }
  float2 bv = *(const float2*)&bias[2 * lane];
  ax += bv.x; ay += bv.y;
  if (RELU) { ax = fmaxf(ax, 0.f); ay = fmaxf(ay, 0.f); }
  float2 o = make_float2(ax, ay);
  *(float2*)&out[(size_t)n * 128 + 2 * lane] = o;
}

// --------------------- SYRK + row/col stats fused (R6) ---------------------

__global__ __launch_bounds__(256) void k_syrkstats(const float* __restrict__ h,
                                                   float* __restrict__ G,
                                                   float* __restrict__ colsum,
                                                   unsigned long long* __restrict__ packed,
                                                   int N, int rowsPer) {
  __shared__ float hs[8][132];
  __shared__ float csS[128];
  __shared__ unsigned long long pkS[8];
  int tid = threadIdx.x;
  int tx = tid & 15, ty = tid >> 4;
  int rr = tid >> 5, c4 = (tid & 31) * 4;
  float acc[8][8];
  #pragma unroll
  for (int i = 0; i < 8; i++)
    #pragma unroll
    for (int j = 0; j < 8; j++) acc[i][j] = 0.f;
  float ca0 = 0.f, ca1 = 0.f, ca2 = 0.f, ca3 = 0.f;
  unsigned long long best = 0;
  if (tid < 128) csS[tid] = 0.f;
  __syncthreads();

  int rstart = blockIdx.x * rowsPer;
  int rend = rstart + rowsPer;
  if (rend > N) rend = N;
  for (int rb = rstart; rb < rend; rb += 8) {
    int gr = rb + rr;
    float4 v = make_float4(0.f, 0.f, 0.f, 0.f);
    if (gr < rend) v = *(const float4*)&h[(size_t)gr * 128 + c4];
    __syncthreads();
    *(float4*)&hs[rr][c4] = v;
    float avx = fabsf(v.x), avy = fabsf(v.y), avz = fabsf(v.z), avw = fabsf(v.w);
    ca0 += avx; ca1 += avy; ca2 += avz; ca3 += avw;
    float rs = (avx + avy) + (avz + avw);
    rs = dpp_add<0xB1>(rs);
    rs = dpp_add<0x4E>(rs);
    rs = dpp_add<0x124>(rs);
    rs = dpp_add<0x128>(rs);
    rs = dpp_add<0x142>(rs);  // lanes 16-31 / 48-63 hold full 32-lane row sums
    if (gr < rend) {
      unsigned long long pk = ((unsigned long long)__float_as_uint(rs) << 32)
                            | (unsigned long long)(0xFFFFFFFFu - (unsigned)gr);
      if (pk > best) best = pk;
    }
    __syncthreads();
    #pragma unroll
    for (int r2 = 0; r2 < 8; r2++) {
      float4 a0 = *(const float4*)&hs[r2][ty * 8];
      float4 a1 = *(const float4*)&hs[r2][ty * 8 + 4];
      float4 b0 = *(const float4*)&hs[r2][tx * 8];
      float4 b1 = *(const float4*)&hs[r2][tx * 8 + 4];
      float a[8] = { a0.x,a0.y,a0.z,a0.w,a1.x,a1.y,a1.z,a1.w };
      float b[8] = { b0.x,b0.y,b0.z,b0.w,b1.x,b1.y,b1.z,b1.w };
      #pragma unroll
      for (int i = 0; i < 8; i++)
        #pragma unroll
        for (int j = 0; j < 8; j++) acc[i][j] += a[i] * b[j];
    }
  }
  if ((tid & 31) == 16) pkS[tid >> 5] = best;
  atomicAdd(&csS[c4 + 0], ca0);
  atomicAdd(&csS[c4 + 1], ca1);
  atomicAdd(&csS[c4 + 2], ca2);
  atomicAdd(&csS[c4 + 3], ca3);
  __syncthreads();
  if (tid == 0) {
    unsigned long long m = pkS[0];
    #pragma unroll
    for (int w = 1; w < 8; w++) if (pkS[w] > m) m = pkS[w];
    atomicMax(packed, m);
  }
  if (tid < 128) atomicAdd(&colsum[tid], csS[tid]);
  #pragma unroll
  for (int i = 0; i < 8; i++)
    #pragma unroll
    for (int j = 0; j < 8; j++)
      atomicAdd(&G[(size_t)(ty * 8 + i) * 128 + tx * 8 + j], acc[i][j]);
}

__global__ void k_extract(const float* __restrict__ h,
                          const unsigned long long* __restrict__ packed,
                          float* __restrict__ hrow, int N) {
  unsigned long long pk = *packed;
  unsigned i = 0xFFFFFFFFu - (unsigned)(pk & 0xFFFFFFFFull);
  if (i >= (unsigned)N) i = 0;
  hrow[threadIdx.x] = h[(size_t)i * 128 + threadIdx.x];
}

// ------------------------------- megastats (1024 threads) ------------------
// One block per stat: 2x (tridiag + bisection) trace-sqrt on 128x128 Gram.
// 8-way column slices: q = tid>>7 (16 cols each), r = tid&127.
// 16 waves/block (4/SIMD) for latency hiding; dependent chains halved.

__global__ __launch_bounds__(1024) void k_megastats5(const float* __restrict__ Gall,
                                                     const float* __restrict__ colall,
                                                     const float* __restrict__ hrowall,
                                                     float* __restrict__ outstats) {
  const int blk = blockIdx.x;
  const float* G = Gall + (size_t)blk * 16384;
  const float* colsum = colall + blk * 128;
  const float* hrowg = hrowall + blk * 128;

  __shared__ __align__(16) float colk[128];
  __shared__ __align__(16) float wwF[256];    // ww[2][128] double buffer
  __shared__ __align__(16) float lamp[16];
  __shared__ float sigp[2];
  __shared__ float diag[128], offd[128];
  __shared__ float asS[128], b2S[128];
  __shared__ float loS[128], hiS[128];
  __shared__ float hiRow[128], gjS[128];
  __shared__ int cntS[1024];
  __shared__ float redw[16];
  __shared__ float scal[16];
  __shared__ int ishared[4];

  const int tid = threadIdx.x;
  const int lane = tid & 63;
  const int wv = tid >> 6;     // wave 0..15
  const int q = tid >> 7;      // slice 0..7 (one wave-pair each)
  const int r = tid & 127;     // row
  const int cbase = q * 16;
  float Areg[16];

  #pragma unroll
  for (int cc = 0; cc < 16; cc++) {
    int c = cbase + cc;
    Areg[cc] = 0.5f * (G[(size_t)r * 128 + c] + G[(size_t)c * 128 + r]);
  }

  for (int solve = 0; solve < 2; solve++) {
    if (q == 0) colk[r] = (r == 0) ? 0.f : Areg[0];
    if (tid == 0) diag[0] = Areg[0];
    if (tid < 256) wwF[tid] = 0.f;
    if (q == 0) {
      float m2 = (r >= 1) ? Areg[0] * Areg[0] : 0.f;
      float s = wave_sum(m2);
      if (lane == 0) sigp[wv] = s;   // wv = 0,1
    }
    __syncthreads();

    for (int k = 0; k <= 125; k++) {
      const int kp1 = k + 1;
      float* wwc = &wwF[(k & 1) * 128];
      float* wwn = &wwF[(1 - (k & 1)) * 128];
      // ---- phase A: scalars, partial p = A v -> ds_add, lambda partials ----
      float sig = sigp[0] + sigp[1];
      float xk1 = colk[kp1];
      float nx = sqrtf(sig);
      float alpha = (xk1 >= 0.f) ? -nx : nx;
      float vns = 2.0f * (sig - alpha * xk1);
      float rvn = (vns > 1e-35f) ? rsqrtf(vns) : 0.f;
      float narvn = -alpha * rvn;
      float ckr = colk[r];
      float vr = ckr * rvn + ((r == kp1) ? narvn : 0.f);
      const bool act = (cbase + 15 >= k);
      float4 cv[4];
      float p = 0.f;
      if (act) {
        const float4* cp = (const float4*)&colk[cbase];  // broadcast reads
        #pragma unroll
        for (int i = 0; i < 4; i++) cv[i] = cp[i];
        if (r >= k) {
          #pragma unroll
          for (int i = 0; i < 4; i++)
            p += Areg[4*i+0]*cv[i].x + Areg[4*i+1]*cv[i].y
               + Areg[4*i+2]*cv[i].z + Areg[4*i+3]*cv[i].w;
          int kl = kp1 - cbase;
          float akp1 = 0.f;
          if (kl >= 0 && kl < 16) {
            #pragma unroll
            for (int i = 0; i < 16; i++) if (i == kl) akp1 = Areg[i];
          }
          p = rvn * p + narvn * akp1;
          atomicAdd(&wwc[r], p);      // ds_add_f32, cross-wave combine
        }
      }
      float lp = vr * p;
      float ls = wave_sum(lp);
      if (lane == 0) lamp[wv] = ls;
      if (tid == 0) offd[k] = alpha;
      __syncthreads();

      // ---- phase B: rank-2 update, extract col k+1, next sigma, zero wwn ----
      float4 l0 = *(const float4*)&lamp[0];
      float4 l1 = *(const float4*)&lamp[4];
      float4 l2 = *(const float4*)&lamp[8];
      float4 l3 = *(const float4*)&lamp[12];
      float lam = (((l0.x + l0.y) + (l0.z + l0.w)) + ((l1.x + l1.y) + (l1.z + l1.w)))
                + (((l2.x + l2.y) + (l2.z + l2.w)) + ((l3.x + l3.y) + (l3.z + l3.w)));
      const int qo = kp1 >> 4;
      float nextc = 0.f;
      if (act && r >= k) {
        float wr = wwc[r];
        float qr = 2.0f * (wr - lam * vr);
        const int kl = kp1 - cbase;
        const float4* wp = (const float4*)&wwc[cbase];   // broadcast reads
        #pragma unroll
        for (int i = 0; i < 4; i++) {
          const int c0 = 4 * i;
          float4 wc = wp[i];
          float v0 = cv[i].x * rvn + ((c0 + 0 == kl) ? narvn : 0.f);
          float v1 = cv[i].y * rvn + ((c0 + 1 == kl) ? narvn : 0.f);
          float v2 = cv[i].z * rvn + ((c0 + 2 == kl) ? narvn : 0.f);
          float v3 = cv[i].w * rvn + ((c0 + 3 == kl) ? narvn : 0.f);
          float q0 = 2.f * (wc.x - lam * v0);
          float q1 = 2.f * (wc.y - lam * v1);
          float q2 = 2.f * (wc.z - lam * v2);
          float q3 = 2.f * (wc.w - lam * v3);
          float a0 = Areg[c0+0] - (vr * q0 + qr * v0); Areg[c0+0] = a0;
          float a1 = Areg[c0+1] - (vr * q1 + qr * v1); Areg[c0+1] = a1;
          float a2 = Areg[c0+2] - (vr * q2 + qr * v2); Areg[c0+2] = a2;
          float a3 = Areg[c0+3] - (vr * q3 + qr * v3); Areg[c0+3] = a3;
          if (c0 + 0 == kl) nextc = a0;
          if (c0 + 1 == kl) nextc = a1;
          if (c0 + 2 == kl) nextc = a2;
          if (c0 + 3 == kl) nextc = a3;
        }
      }
      if (q == qo && r >= k) colk[r] = (r <= kp1) ? 0.f : nextc;
      if (q == qo && r == kp1) diag[kp1] = nextc;
      if (q == qo) {
        float m2 = (r > kp1 && r >= k) ? nextc * nextc : 0.f;
        float s = wave_sum(m2);
        if (lane == 0) sigp[wv & 1] = s;
      }
      if (q == 1) wwn[r] = 0.f;   // zero next buffer
      __syncthreads();
    }
    if (tid == 0) offd[126] = colk[127];
    if (q == 7 && r == 127) diag[127] = Areg[15];
    __syncthreads();

    // ---- Gershgorin bound ----
    if (tid < 128) {
      float t = fabsf(diag[tid]);
      if (tid > 0) t += fabsf(offd[tid - 1]);
      if (tid < 127) t += fabsf(offd[tid]);
      #pragma unroll
      for (int m = 32; m >= 1; m >>= 1) t = fmaxf(t, __shfl_xor(t, m));
      if (lane == 0) redw[wv] = t;
    }
    __syncthreads();
    if (tid == 0) {
      float g = fmaxf(redw[0], redw[1]);
      if (!(g > 1e-30f)) g = 1.f;
      scal[3] = g; scal[5] = 1.0f / g;
    }
    __syncthreads();
    if (tid < 128) {
      float ginv = scal[5];
      asS[tid] = diag[tid] * ginv;
      float ob = (tid < 127) ? offd[tid] * ginv : 0.f;
      b2S[tid] = ob * ob;
      loS[tid] = -0.0625f;
      hiS[tid] = 1.03125f;
    }
    __syncthreads();

    // ---- multisection bisection (8 probes per eigenvalue per round) ----
    for (int round = 0; round < 9; round++) {
      int kk = tid & 127;
      int t = tid >> 7;           // 0..7
      float l = loS[kk], h2v = hiS[kk];
      float sigma = l + (h2v - l) * (1.0f / 9.0f) * (float)(t + 1);
      const float PIV = 1e-20f;
      float d = asS[0] - sigma;
      if (fabsf(d) < PIV) d = -PIV;
      int cnt = (d < 0.f) ? 1 : 0;
      for (int i = 1; i < 128; i++) {
        d = (asS[i] - sigma) - b2S[i - 1] * __builtin_amdgcn_rcpf(d);
        if (fabsf(d) < PIV) d = -PIV;
        cnt += (d < 0.f) ? 1 : 0;
      }
      cntS[tid] = cnt;
      __syncthreads();
      if (tid < 128) {
        float l2 = loS[tid], h2 = hiS[tid];
        float w = (h2 - l2) * (1.0f / 9.0f);
        int cross = 8;
        #pragma unroll
        for (int t2 = 7; t2 >= 0; t2--) {
          if (cntS[tid + (t2 << 7)] > tid) cross = t2;
        }
        loS[tid] = l2 + w * (float)cross;
        hiS[tid] = (cross == 8) ? h2 : l2 + w * (float)(cross + 1);
      }
      __syncthreads();
    }
    // ---- sum sqrt eigenvalues ----
    if (tid < 128) {
      float lam2 = 0.5f * (loS[tid] + hiS[tid]);
      lam2 = fmaxf(lam2, 0.f) * scal[3];
      float s = sqrtf(lam2);
      #pragma unroll
      for (int m = 32; m >= 1; m >>= 1) s += __shfl_xor(s, m);
      if (lane == 0) redw[wv] = s;
    }
    __syncthreads();
    if (tid == 0) scal[4] = redw[0] + redw[1];
    __syncthreads();

    if (solve == 0) {
      if (tid < 128) hiRow[tid] = hrowg[tid];
      __syncthreads();
      if (tid < 128) {
        float v = colsum[tid];
        int idx = tid;
        #pragma unroll
        for (int m = 32; m >= 1; m >>= 1) {
          float v2 = __shfl_xor(v, m);
          int i2 = __shfl_xor(idx, m);
          if (v2 > v || (v2 == v && i2 < idx)) { v = v2; idx = i2; }
        }
        if (lane == 0) { redw[wv] = v; ishared[wv] = idx; }
        float hv = hiRow[tid];
        float nh = hv * hv;
        #pragma unroll
        for (int m = 32; m >= 1; m >>= 1) nh += __shfl_xor(nh, m);
        if (lane == 0) redw[4 + wv] = nh;
      }
      __syncthreads();
      if (tid == 0) {
        float v0 = redw[0], v1 = redw[1];
        int j = (v1 > v0 || (v1 == v0 && ishared[1] < ishared[0])) ? ishared[1] : ishared[0];
        float nh2 = redw[4] + redw[5];
        float nu = scal[4];
        float Gjj = G[(size_t)j * 128 + j];
        float hij = hiRow[j];
        float sflip = (hij < 0.f) ? -1.f : 1.f;
        scal[6] = 1.0f / (nu * nu);
        scal[7] = sflip / (nu * sqrtf(Gjj) * sqrtf(nh2));
        scal[8] = 1.0f / nh2;
        ishared[2] = j;
      }
      __syncthreads();
      int j = ishared[2];
      if (tid < 128) gjS[tid] = 0.5f * (G[(size_t)tid * 128 + j] + G[(size_t)j * 128 + tid]);
      __syncthreads();
      float inv2 = scal[6], c1 = scal[7], c2 = scal[8];
      float gr_ = gjS[r], hr_ = hiRow[r];
      #pragma unroll
      for (int cc = 0; cc < 16; cc++) {
        int c = cbase + cc;
        float gsym = 0.5f * (G[(size_t)r * 128 + c] + G[(size_t)c * 128 + r]);
        Areg[cc] = gsym * inv2 - c1 * (gr_ * hiRow[c] + hr_ * gjS[c]) + c2 * hr_ * hiRow[c];
      }
      __syncthreads();
    }
  }
  if (tid == 0) outstats[blk] = scal[4];
}

// ------------------------------- host driver -------------------------------

extern "C" void kernel_launch(void* const* d_in, const int* in_sizes, int n_in,
                              void* d_out, int out_size, void* d_ws, size_t ws_size,
                              hipStream_t stream) {
  const float* x = (const float*)d_in[0];
  const int* edge = (const int*)d_in[1];
  const float* encW = (const float*)d_in[2];
  const float* encb = (const float*)d_in[3];
  const float* W0 = (const float*)d_in[4];
  const float* b0 = (const float*)d_in[5];
  const float* W1 = (const float*)d_in[6];
  const float* b1 = (const float*)d_in[7];
  const float* W2 = (const float*)d_in[8];
  const float* b2 = (const float*)d_in[9];

  const int N = in_sizes[0] / 128;
  const int E = in_sizes[1] / 2;
  const int* esrc = edge;
  const int* edst = edge + E;

  float* out = (float*)d_out;
  float* stats_out = out + (size_t)N * 128;

  char* ws = (char*)d_ws;
  size_t offTmp = 0;
  size_t offG = offTmp + (size_t)N * 128 * 4;
  size_t offCol = offG + 4 * 16384 * 4;
  size_t offPkd = offCol + 4 * 128 * 4;
  size_t offHrow = offPkd + 4 * 8;
  size_t offDeg = offHrow + 4 * 128 * 4;
  size_t offRp = offDeg + (size_t)N * 4;
  size_t offCur = offRp + (size_t)(N + 1) * 4;
  size_t offDinv = offCur + (size_t)N * 4;
  size_t offSrc = offDinv + (size_t)N * 4;
  size_t offNrm = offSrc + (size_t)E * 4;
  size_t offPart = offNrm + (size_t)E * 4;
  size_t total = offPart + 256;
  if (ws_size < total) return;

  float* tmp = (float*)(ws + offTmp);
  float* Gall = (float*)(ws + offG);
  float* colall = (float*)(ws + offCol);
  unsigned long long* pkdall = (unsigned long long*)(ws + offPkd);
  float* hrowall = (float*)(ws + offHrow);
  unsigned* deg = (unsigned*)(ws + offDeg);
  unsigned* rowptr = (unsigned*)(ws + offRp);
  unsigned* cursor = (unsigned*)(ws + offCur);
  float* dinv = (float*)(ws + offDinv);
  int* srcs = (int*)(ws + offSrc);
  float* nrm = (float*)(ws + offNrm);
  unsigned* part = (unsigned*)(ws + offPart);

  hipMemsetAsync(ws + offG, 0, 4 * 16384 * 4 + 4 * 128 * 4 + 4 * 8, stream);
  hipMemsetAsync(ws + offDeg, 0, (size_t)N * 4, stream);

  const int EB = (E + 255) / 256;
  const int NB4 = (N + 3) / 4;
  const int GB = (N + 127) / 128;
  const int SB = (N + 1023) / 1024;
  const int SYB = 256;
  const int syrkRows = (N + SYB - 1) / SYB;

  k_deg<<<EB, 256, 0, stream>>>(edst, deg, E);
  k_scan1<<<SB, 1024, 0, stream>>>(deg, cursor, part, N);
  k_scan2<<<1, 64, 0, stream>>>(part, SB);
  k_scan3<<<SB, 1024, 0, stream>>>(deg, part, rowptr, cursor, dinv, N, SB);
  k_scatter<<<EB, 256, 0, stream>>>(esrc, edst, dinv, cursor, srcs, nrm, E);

  // encoder: h0 = x @ encW.T + encb  -> d_out
  k_gemm<<<GB, 256, 0, stream>>>(x, encW, encb, out, N);
  k_syrkstats<<<SYB, 256, 0, stream>>>(out, Gall + 0 * 16384, colall + 0 * 128, pkdall + 0, N, syrkRows);
  k_extract<<<1, 128, 0, stream>>>(out, pkdall + 0, hrowall + 0 * 128, N);

  // layer 0
  k_gemm<<<GB, 256, 0, stream>>>(out, W0, nullptr, tmp, N);
  k_agg<true><<<NB4, 256, 0, stream>>>(tmp, rowptr, srcs, nrm, b0, out, N);
  k_syrkstats<<<SYB, 256, 0, stream>>>(out, Gall + 1 * 16384, colall + 1 * 128, pkdall + 1, N, syrkRows);
  k_extract<<<1, 128, 0, stream>>>(out, pkdall + 1, hrowall + 1 * 128, N);

  // layer 1
  k_gemm<<<GB, 256, 0, stream>>>(out, W1, nullptr, tmp, N);
  k_agg<true><<<NB4, 256, 0, stream>>>(tmp, rowptr, srcs, nrm, b1, out, N);
  k_syrkstats<<<SYB, 256, 0, stream>>>(out, Gall + 2 * 16384, colall + 2 * 128, pkdall + 2, N, syrkRows);
  k_extract<<<1, 128, 0, stream>>>(out, pkdall + 2, hrowall + 2 * 128, N);

  // layer 2 (no relu)
  k_gemm<<<GB, 256, 0, stream>>>(out, W2, nullptr, tmp, N);
  k_agg<false><<<NB4, 256, 0, stream>>>(tmp, rowptr, srcs, nrm, b2, out, N);
  k_syrkstats<<<SYB, 256, 0, stream>>>(out, Gall + 3 * 16384, colall + 3 * 128, pkdall + 3, N, syrkRows);
  k_extract<<<1, 128, 0, stream>>>(out, pkdall + 3, hrowall + 3 * 128, N);

  // all four stats concurrently (4 blocks on 4 CUs)
  k_megastats5<<<4, 1024, 0, stream>>>(Gall, colall, hrowall, stats_out);
}